// Round 4
// baseline (239.678 us; speedup 1.0000x reference)
//
#include <hip/hip_runtime.h>
#include <hip/hip_cooperative_groups.h>
#include <math.h>

namespace cg = cooperative_groups;

// Capsule routing, B=32, N=1024, D=256, NC=32, DC=64. Factored algebra
// (never materialize u_hat):
//   t[b,i,k]  = sum_j c[b,i,j] U[b,j,k]        (ctu / p0 colmean for iter 0)
//   s[b,i,d]  = sum_k t[b,i,k] W[k,i*64+d]     (sv)
//   v = s/sqrt(||s||^2+eps); w[k] = W_i v      (sv)
//   b[b,i,j] += U w  -> emat=exp(b), sef=sum   (bupd, fused softmax denom)
// One cooperative kernel (512 blk x 256 thr, grid.sync between phases),
// 32 KB static LDS so the runtime's coop co-residency check passes at
// 2 blocks/CU even under a 64 KB/CU shared-mem model. Fallback: same
// phases as 8 plain launches if the pre-check fails.

#define SMEM_F 8192   // 32 KB

// ---------------------------------------------------------------------------
// P0: colmean partials (uniform c): t0p[b][q][k] = (1/1024)*sum of 64 j rows.
// Block 511 also zeroes sef[0..2047] (both iteration buffers).
__device__ __forceinline__ void p0_phase(const float* __restrict__ U,
                                         float* __restrict__ t0p,
                                         float* __restrict__ sef,
                                         int bid, int tid) {
    int b = bid >> 4, q = bid & 15;
    const float* Up = U + (((b << 10) + (q << 6)) << 8) + tid;
    float acc = 0.f;
    #pragma unroll 16
    for (int jl = 0; jl < 64; ++jl) acc += Up[jl << 8];
    t0p[(b << 12) + (q << 8) + tid] = acc * (1.0f / 1024.0f);
    if (bid == 511) {
        #pragma unroll
        for (int qq = 0; qq < 8; ++qq) sef[(qq << 8) + tid] = 0.f;
    }
}

// ---------------------------------------------------------------------------
// sv: per (b,i): t[k] = sum of 16 partials; s[d] = sum_k t[k] W[k,i*64+d];
// v = s/sqrt(||s||2+eps); w[k] = sum_d W[k,i*64+d] v[d] -> wbt[b][k][i]
__device__ __forceinline__ void sv_phase(const float* __restrict__ t0p,
                                         const float* __restrict__ tp,
                                         int mode,
                                         const float* __restrict__ W,
                                         float* __restrict__ vout,
                                         float* __restrict__ wbt,
                                         int bi, int tid, float* smem) {
    float* t_lds = smem;          // 256
    float* spart = smem + 256;    // 256
    float* v_lds = smem + 512;    // 64
    int b = bi >> 5, i = bi & 31;

    const float* tb;
    int pstr;
    if (mode == 0) { tb = t0p + (b << 12) + tid; pstr = 256;    }  // t0p[b][q][k]
    else           { tb = tp + (bi << 8) + tid;  pstr = 262144; }  // tp[p][bi][k]
    float acc = 0.f;
    #pragma unroll
    for (int p = 0; p < 16; ++p) acc += tb[p * pstr];
    __syncthreads();              // guard smem reuse from previous phase
    t_lds[tid] = acc;
    __syncthreads();

    // s phase: thread = (d = tid&63, kq = tid>>6)
    int d = tid & 63, kq = tid >> 6;
    const float* Wc = W + ((kq << 6) * 2048) + i * 64 + d;
    float s = 0.f;
    #pragma unroll 4
    for (int kk = 0; kk < 64; ++kk)
        s += t_lds[(kq << 6) + kk] * Wc[kk * 2048];
    spart[tid] = s;
    __syncthreads();

    if (tid < 64) {
        float sv = spart[tid] + spart[tid + 64] + spart[tid + 128] + spart[tid + 192];
        float n2 = sv * sv;
        #pragma unroll
        for (int off = 1; off < 64; off <<= 1) n2 += __shfl_xor(n2, off, 64);
        float v = sv / sqrtf(n2 + 1e-7f);
        if (vout) vout[(bi << 6) + tid] = v;
        v_lds[tid] = v;
    }
    __syncthreads();

    // w phase: thread = k
    const float4* Wr = (const float4*)(W + tid * 2048 + i * 64);
    const float4* v4 = (const float4*)v_lds;
    float w = 0.f;
    #pragma unroll
    for (int q = 0; q < 16; ++q) {
        float4 a = Wr[q], vv = v4[q];
        w += a.x * vv.x + a.y * vv.y + a.z * vv.z + a.w * vv.w;
    }
    wbt[(b << 13) + (tid << 5) + i] = w;   // [b][k][i]
    __syncthreads();
}

// ---------------------------------------------------------------------------
// bupd: for 2 chunks of 32 j: delta[i][j] = sum_k w[i][k] U[b,j,k];
// emat = (addold? emat:1)*exp(delta); sef[b*32+i] += row sums (atomic).
// thread = (j = tid&31, ig = tid>>5 -> 4 i's). w staged in k-halves (16 KB)
// so total LDS = 32 KB.
__device__ __forceinline__ void bupd_phase(const float* __restrict__ U,
                                           const float* __restrict__ wbt,
                                           float* __restrict__ emat,
                                           float* __restrict__ sef,
                                           int addold, int b, int jc2,
                                           int tid, float* smem) {
    float4* wl4 = (float4*)smem;            // [klocal=128][ig=8] f4 (16 KB)
    float4* Ul4 = (float4*)(smem + 4096);   // [j=32][32 f4] swizzled (16 KB)
    int j = tid & 31, ig = tid >> 5;
    const float4* wsrc = (const float4*)(wbt + (b << 13));
    const float4* U4 = (const float4*)U;

    float acc[2][4] = {{0.f, 0.f, 0.f, 0.f}, {0.f, 0.f, 0.f, 0.f}};

    for (int s = 0; s < 2; ++s) {
        __syncthreads();   // prev-phase / prev-s readers done before wl overwrite
        for (int idx = tid; idx < 1024; idx += 256)
            wl4[idx] = wsrc[(s << 10) + idx];
        for (int cc = 0; cc < 2; ++cc) {
            int jc = (jc2 << 1) + cc;
            __syncthreads();   // covers wl visibility + prev Ul readers
            for (int idx = tid; idx < 1024; idx += 256) {
                int jl = idx >> 5, k4 = idx & 31;
                Ul4[(jl << 5) + ((k4 + jl) & 31)] =
                    U4[(((b << 10) + (jc << 5) + jl) << 6) + (s << 5) + k4];
            }
            __syncthreads();
            #pragma unroll
            for (int k4 = 0; k4 < 32; ++k4) {
                float4 u4 = Ul4[(j << 5) + ((k4 + j) & 31)];
                float uu[4] = {u4.x, u4.y, u4.z, u4.w};
                #pragma unroll
                for (int r = 0; r < 4; ++r) {
                    float4 w4 = wl4[(((k4 << 2) + r) << 3) + ig];
                    acc[cc][0] += w4.x * uu[r];
                    acc[cc][1] += w4.y * uu[r];
                    acc[cc][2] += w4.z * uu[r];
                    acc[cc][3] += w4.w * uu[r];
                }
            }
        }
    }

    #pragma unroll
    for (int cc = 0; cc < 2; ++cc) {
        int jg = (((jc2 << 1) + cc) << 5) + j;
        #pragma unroll
        for (int q = 0; q < 4; ++q) {
            int i = (ig << 2) + q;
            long off = (long)(((b << 5) + i) << 10) + jg;
            float e = __expf(acc[cc][q]);
            if (addold) e *= emat[off];
            emat[off] = e;
            float se = e;
            #pragma unroll
            for (int m = 1; m < 32; m <<= 1) se += __shfl_xor(se, m, 64);
            if (j == 0) atomicAdd(&sef[(b << 5) + i], se);
        }
    }
}

// ---------------------------------------------------------------------------
// ctu: tp[p][b][i][k] = sum_{jl in 64-chunk p} c[b,i,j] U[b,j,k], c = emat/sef.
// thread = (kk = tid&127 -> k's {kk, kk+128}, jh = tid>>7 -> 32-j half).
// Cross-jh reduce in 2 rounds through a 128x33 buffer (LDS total 26 KB).
__device__ __forceinline__ void ctu_phase(const float* __restrict__ U,
                                          const float* __restrict__ emat,
                                          const float* __restrict__ sef,
                                          float* __restrict__ tp,
                                          int b, int p, int tid, float* smem) {
    float* c_lds = smem;           // [jl=64][36 pad] = 2304
    float* rse   = smem + 2304;    // 32
    float* red   = smem + 2336;    // [kk=128][33] = 4224
    int kk = tid & 127, jh = tid >> 7;

    __syncthreads();               // guard smem reuse
    if (tid < 32) rse[tid] = 1.0f / sef[(b << 5) + tid];
    __syncthreads();
    for (int idx = tid; idx < 2048; idx += 256) {
        int i = idx >> 6, jl = idx & 63;
        c_lds[jl * 36 + i] =
            emat[(long)(((b << 5) + i) << 10) + (p << 6) + jl] * rse[i];
    }
    __syncthreads();

    float acc0[32], acc1[32];
    #pragma unroll
    for (int i = 0; i < 32; ++i) { acc0[i] = 0.f; acc1[i] = 0.f; }

    const float4* c4base = (const float4*)c_lds;   // 9 f4 per j-row
    for (int sub = 0; sub < 2; ++sub) {
        int jlo = (jh << 5) + (sub << 4);
        const float* Up = U + (((b << 10) + (p << 6) + jlo) << 8) + kk;
        float u0[16], u1[16];
        #pragma unroll
        for (int jj = 0; jj < 16; ++jj) {
            u0[jj] = Up[jj << 8];
            u1[jj] = Up[(jj << 8) + 128];
        }
        #pragma unroll
        for (int jj = 0; jj < 16; ++jj) {
            const float4* c4 = c4base + (jlo + jj) * 9;
            float ua = u0[jj], ub = u1[jj];
            #pragma unroll
            for (int ii = 0; ii < 8; ++ii) {
                float4 c = c4[ii];             // wave-uniform broadcast
                acc0[ii * 4 + 0] += c.x * ua;  acc1[ii * 4 + 0] += c.x * ub;
                acc0[ii * 4 + 1] += c.y * ua;  acc1[ii * 4 + 1] += c.y * ub;
                acc0[ii * 4 + 2] += c.z * ua;  acc1[ii * 4 + 2] += c.z * ub;
                acc0[ii * 4 + 3] += c.w * ua;  acc1[ii * 4 + 3] += c.w * ub;
            }
        }
    }

    __syncthreads();
    if (jh == 0) {
        #pragma unroll
        for (int i = 0; i < 32; ++i) red[kk * 33 + i] = acc0[i];
    }
    __syncthreads();
    if (jh == 1) {
        #pragma unroll
        for (int i = 0; i < 32; ++i) {
            long o = ((long)((p << 10) + (b << 5) + i)) << 8;
            tp[o + kk] = red[kk * 33 + i] + acc0[i];
        }
    }
    __syncthreads();
    if (jh == 0) {
        #pragma unroll
        for (int i = 0; i < 32; ++i) red[kk * 33 + i] = acc1[i];
    }
    __syncthreads();
    if (jh == 1) {
        #pragma unroll
        for (int i = 0; i < 32; ++i) {
            long o = ((long)((p << 10) + (b << 5) + i)) << 8;
            tp[o + kk + 128] = red[kk * 33 + i] + acc1[i];
        }
    }
}

// ---------------------------------------------------------------------------
__global__ __launch_bounds__(256, 2) void k_fused(const float* __restrict__ U,
                                                  const float* __restrict__ W,
                                                  float* __restrict__ out,
                                                  float* __restrict__ tp,
                                                  float* __restrict__ t0p,
                                                  float* __restrict__ emat,
                                                  float* __restrict__ wbt,
                                                  float* __restrict__ sef) {
    cg::grid_group grid = cg::this_grid();
    __shared__ __align__(16) float smem[SMEM_F];
    const int bid = blockIdx.x, tid = threadIdx.x;
    const int b16 = bid >> 4, q16 = bid & 15;

    p0_phase(U, t0p, sef, bid, tid);
    grid.sync();
    sv_phase(t0p, tp, 0, W, nullptr, wbt, bid * 2, tid, smem);
    sv_phase(t0p, tp, 0, W, nullptr, wbt, bid * 2 + 1, tid, smem);
    grid.sync();
    bupd_phase(U, wbt, emat, sef, 0, b16, q16, tid, smem);
    grid.sync();
    ctu_phase(U, emat, sef, tp, b16, q16, tid, smem);
    grid.sync();
    sv_phase(t0p, tp, 1, W, nullptr, wbt, bid * 2, tid, smem);
    sv_phase(t0p, tp, 1, W, nullptr, wbt, bid * 2 + 1, tid, smem);
    grid.sync();
    bupd_phase(U, wbt, emat, sef + 1024, 1, b16, q16, tid, smem);
    grid.sync();
    ctu_phase(U, emat, sef + 1024, tp, b16, q16, tid, smem);
    grid.sync();
    sv_phase(t0p, tp, 1, W, out, wbt, bid * 2, tid, smem);
    sv_phase(t0p, tp, 1, W, out, wbt, bid * 2 + 1, tid, smem);
}

// ----------------------- fallback plain kernels ----------------------------
__global__ __launch_bounds__(256, 2) void fb_p0(const float* __restrict__ U,
                                                float* __restrict__ t0p,
                                                float* __restrict__ sef) {
    p0_phase(U, t0p, sef, blockIdx.x, threadIdx.x);
}
__global__ __launch_bounds__(256, 2) void fb_sv(const float* __restrict__ t0p,
                                                const float* __restrict__ tp, int mode,
                                                const float* __restrict__ W,
                                                float* __restrict__ vout,
                                                float* __restrict__ wbt) {
    __shared__ __align__(16) float smem[SMEM_F];
    sv_phase(t0p, tp, mode, W, vout, wbt, blockIdx.x * 2, threadIdx.x, smem);
    sv_phase(t0p, tp, mode, W, vout, wbt, blockIdx.x * 2 + 1, threadIdx.x, smem);
}
__global__ __launch_bounds__(256, 2) void fb_bupd(const float* __restrict__ U,
                                                  const float* __restrict__ wbt,
                                                  float* __restrict__ emat,
                                                  float* __restrict__ sef, int addold) {
    __shared__ __align__(16) float smem[SMEM_F];
    bupd_phase(U, wbt, emat, sef, addold, blockIdx.x >> 4, blockIdx.x & 15,
               threadIdx.x, smem);
}
__global__ __launch_bounds__(256, 2) void fb_ctu(const float* __restrict__ U,
                                                 const float* __restrict__ emat,
                                                 const float* __restrict__ sef,
                                                 float* __restrict__ tp) {
    __shared__ __align__(16) float smem[SMEM_F];
    ctu_phase(U, emat, sef, tp, blockIdx.x >> 4, blockIdx.x & 15, threadIdx.x, smem);
}

// ---------------------------------------------------------------------------
extern "C" void kernel_launch(void* const* d_in, const int* in_sizes, int n_in,
                              void* d_out, int out_size, void* d_ws, size_t ws_size,
                              hipStream_t stream) {
    const float* U = (const float*)d_in[0];   // [32,1024,256]
    const float* W = (const float*)d_in[1];   // [256,2048]
    float* out = (float*)d_out;               // [32,32,64]
    float* ws = (float*)d_ws;

    // ws layout (floats); total 5,638,144 = 22.6 MB (ws is ~256 MB)
    float* tp   = ws;                  // [16][1024][256] = 4,194,304
    float* t0p  = tp + 4194304;        // [32][16][256]   =   131,072
    float* emat = t0p + 131072;        // [32][32][1024]  = 1,048,576
    float* wbt  = emat + 1048576;      // [32][256][32]   =   262,144
    float* sef  = wbt + 262144;        // [2][1024]       =     2,048

    // capture-safe, deterministic path selection (same result every call)
    int dev = 0;
    hipGetDevice(&dev);
    int coop = 0, nCU = 0, maxBlk = 0;
    hipDeviceGetAttribute(&coop, hipDeviceAttributeCooperativeLaunch, dev);
    hipDeviceGetAttribute(&nCU, hipDeviceAttributeMultiprocessorCount, dev);
    hipError_t oe = hipOccupancyMaxActiveBlocksPerMultiprocessor(&maxBlk, k_fused, 256, 0);

    if (coop && oe == hipSuccess && (long)maxBlk * nCU >= 512) {
        void* args[] = {(void*)&U, (void*)&W, (void*)&out, (void*)&tp,
                        (void*)&t0p, (void*)&emat, (void*)&wbt, (void*)&sef};
        if (hipLaunchCooperativeKernel((const void*)k_fused, dim3(512), dim3(256),
                                       args, 0, stream) == hipSuccess)
            return;
    }

    // fallback: identical phases as 8 plain launches
    fb_p0<<<512, 256, 0, stream>>>(U, t0p, sef);
    fb_sv<<<512, 256, 0, stream>>>(t0p, tp, 0, W, nullptr, wbt);
    fb_bupd<<<512, 256, 0, stream>>>(U, wbt, emat, sef, 0);
    fb_ctu<<<512, 256, 0, stream>>>(U, emat, sef, tp);
    fb_sv<<<512, 256, 0, stream>>>(t0p, tp, 1, W, nullptr, wbt);
    fb_bupd<<<512, 256, 0, stream>>>(U, wbt, emat, sef + 1024, 1);
    fb_ctu<<<512, 256, 0, stream>>>(U, emat, sef + 1024, tp);
    fb_sv<<<512, 256, 0, stream>>>(t0p, tp, 1, W, out, wbt);
}

// Round 5
// 220.186 us; speedup vs baseline: 1.0885x; 1.0885x over previous
//
#include <hip/hip_runtime.h>
#include <math.h>

// Capsule routing B=32, N=1024, D=256, NC=32, DC=64, factored (no u_hat):
//   delta[i][j] = w_i . U[b,j,:]      w_i = W_i v_i   (256-dot)
//   e = exp(b_logit), sef = sum_j e,  t[i][k] = sum_j e * U[b,j,k]
//   v = t / sqrt(||t||^2 + eps*sef^2)   (normalization folded into squash)
// Key: capsules are INDEPENDENT per (b,i) -> one plain kernel, grid (32 b x 8 ig),
// 4 capsules/block, block=1024, all coupling via __syncthreads. No grid.sync,
// no atomics. U[b] streamed twice from L2 via double-buffered LDS tiles.
// blockIdx decode b=idx&31 keeps same-b blocks on one XCD (idx%8 == b%8).

#define RSTR 65           // Ubuf row stride in float4 (65*16B rows kill phase-A conflicts)
#define TJ 32             // j rows per tile

// ---------------------------------------------------------------------------
// colsum partials for iteration 0 (uniform c): t0p[b][q][k], q=0..15
__global__ __launch_bounds__(256) void k_colsum(const float* __restrict__ U,
                                                float* __restrict__ t0p) {
    int b = blockIdx.x, q = blockIdx.y, k = threadIdx.x;
    const float* Up = U + (((b << 10) + (q << 6)) << 8) + k;
    float acc = 0.f;
    #pragma unroll 16
    for (int jl = 0; jl < 64; ++jl) acc += Up[jl << 8];
    t0p[(b << 12) + (q << 8) + k] = acc * (1.0f / 1024.0f);
}

// ---------------------------------------------------------------------------
// sv: s[i][d] = sum_k t[i*tstr+k] W[k][iglob*64+d]; v = s*rsqrt(||s||^2+eps*sef^2);
// w[i][k] = sum_d W[k][iglob*64+d] v[d] -> w_lds[i][k]
__device__ __forceinline__ void sv_block(const float* __restrict__ W,
                                         const float* trow, int tstr,
                                         const float* sef_lds, int usesef,
                                         float* spart, float* v_lds, float* w_lds,
                                         float* outp, int writeOut,
                                         int b, int ig, int tid) {
    int d = tid & 63, g = tid >> 6;       // g = i*4 + kq
    int i = g >> 2, kq = g & 3;
    const float* Wp = W + ((kq << 6) * 2048) + (((ig << 2) + i) << 6) + d;
    const float* tr = trow + i * tstr + (kq << 6);
    float s = 0.f;
    #pragma unroll 8
    for (int kk = 0; kk < 64; ++kk) s += tr[kk] * Wp[kk * 2048];
    spart[tid] = s;                        // layout [i][kq][d]
    __syncthreads();
    if (tid < 256) {
        int dd = tid & 63, ii = tid >> 6;
        float sv = spart[(ii << 8) + dd] + spart[(ii << 8) + 64 + dd]
                 + spart[(ii << 8) + 128 + dd] + spart[(ii << 8) + 192 + dd];
        float n2 = sv * sv;
        #pragma unroll
        for (int m = 1; m < 64; m <<= 1) n2 += __shfl_xor(n2, m, 64);
        float sf = usesef ? sef_lds[ii] : 1.0f;
        float v = sv * rsqrtf(n2 + 1e-7f * sf * sf);
        v_lds[(ii << 6) + dd] = v;
        if (writeOut) outp[(((b << 5) + (ig << 2) + ii) << 6) + dd] = v;
    }
    __syncthreads();
    int k = tid & 255, ii = tid >> 8;
    const float4* Wr = (const float4*)(W + k * 2048 + (((ig << 2) + ii) << 6));
    const float4* v4 = (const float4*)(v_lds + (ii << 6));
    float w = 0.f;
    #pragma unroll
    for (int q = 0; q < 16; ++q) {
        float4 a = Wr[q], vv = v4[q];
        w += a.x * vv.x + a.y * vv.y + a.z * vv.z + a.w * vv.w;
    }
    w_lds[(ii << 8) + k] = w;              // [i][k]
    __syncthreads();
}

// ---------------------------------------------------------------------------
// One routing pass over U[b]: per 32-j tile (double-buffered LDS):
//  phase A: thread(kq=tid&31, jl=tid>>5): dp[i] over 8 k from regs-held w;
//           butterfly over kq (in-wave, bits 0..4) -> full delta; kq==0 lanes
//           do bmat +/- , exp, e_lds write, sef accumulation.
//  phase B: thread(k4=tid&63, jh=tid>>6): acc[i] += e[j][i]*u4 for 2 j.
// Pass end: jh-reduce acc through scrB (aliases Ubuf) -> t_lds; sef partials -> sef_lds.
__device__ __forceinline__ void routing_pass(const float4* __restrict__ U4b,
                                             float4* Ubuf, float* bmat,
                                             float* e_lds, float* sefp,
                                             float* sef_lds, float* t_lds,
                                             const float* w_lds,
                                             int addold, int tid) {
    int kq = tid & 31, jl5 = tid >> 5;
    const float4* wl4 = (const float4*)w_lds;
    float4 w4r[4][2];
    #pragma unroll
    for (int i = 0; i < 4; ++i) {
        w4r[i][0] = wl4[(i << 6) + (kq << 1)];
        w4r[i][1] = wl4[(i << 6) + (kq << 1) + 1];
    }
    float4 acc[4];
    #pragma unroll
    for (int i = 0; i < 4; ++i) acc[i] = make_float4(0.f, 0.f, 0.f, 0.f);
    float sefacc[4] = {0.f, 0.f, 0.f, 0.f};

    // prologue: stage tile 0 into buffer 0 (wave = one 64-f4 row)
    Ubuf[(tid >> 6) * RSTR + (tid & 63)] = U4b[tid];
    Ubuf[((tid >> 6) + 16) * RSTR + (tid & 63)] = U4b[tid + 1024];

    for (int t = 0; t < 32; ++t) {
        __syncthreads();                              // B0: stage(t) visible; subB(t-1) done
        float4 g0, g1;
        if (t < 31) {
            const float4* src = U4b + (((t + 1) << 5) << 6);
            g0 = src[tid];
            g1 = src[tid + 1024];
        }
        const float4* ub = Ubuf + (t & 1) * (TJ * RSTR);
        // phase A
        float4 u0 = ub[jl5 * RSTR + (kq << 1)];
        float4 u1 = ub[jl5 * RSTR + (kq << 1) + 1];
        float dp[4];
        #pragma unroll
        for (int i = 0; i < 4; ++i)
            dp[i] = w4r[i][0].x * u0.x + w4r[i][0].y * u0.y + w4r[i][0].z * u0.z + w4r[i][0].w * u0.w
                  + w4r[i][1].x * u1.x + w4r[i][1].y * u1.y + w4r[i][1].z * u1.z + w4r[i][1].w * u1.w;
        #pragma unroll
        for (int m = 1; m < 32; m <<= 1) {
            #pragma unroll
            for (int i = 0; i < 4; ++i) dp[i] += __shfl_xor(dp[i], m, 64);
        }
        if (kq == 0) {
            int jg = (t << 5) + jl5;
            float ev[4];
            #pragma unroll
            for (int i = 0; i < 4; ++i) {
                float d2 = dp[i];
                if (addold) d2 += bmat[(i << 10) + jg];
                else        bmat[(i << 10) + jg] = d2;
                ev[i] = __expf(d2);
                sefacc[i] += ev[i];
            }
            ((float4*)e_lds)[jl5] = make_float4(ev[0], ev[1], ev[2], ev[3]);
        }
        if (t < 31) {
            float4* dst = Ubuf + ((t + 1) & 1) * (TJ * RSTR);
            dst[(tid >> 6) * RSTR + (tid & 63)] = g0;
            dst[((tid >> 6) + 16) * RSTR + (tid & 63)] = g1;
        }
        __syncthreads();                              // B1: e_lds + stage(t+1) visible
        // phase B
        int k4 = tid & 63, jh = tid >> 6;
        #pragma unroll
        for (int jj = 0; jj < 2; ++jj) {
            int j = (jh << 1) + jj;
            float4 u = ub[j * RSTR + k4];
            float4 e = ((const float4*)e_lds)[j];
            acc[0].x += e.x * u.x; acc[0].y += e.x * u.y; acc[0].z += e.x * u.z; acc[0].w += e.x * u.w;
            acc[1].x += e.y * u.x; acc[1].y += e.y * u.y; acc[1].z += e.y * u.z; acc[1].w += e.y * u.w;
            acc[2].x += e.z * u.x; acc[2].y += e.z * u.y; acc[2].z += e.z * u.z; acc[2].w += e.z * u.w;
            acc[3].x += e.w * u.x; acc[3].y += e.w * u.y; acc[3].z += e.w * u.z; acc[3].w += e.w * u.w;
        }
    }
    __syncthreads();                                  // all phase-B reads done -> alias Ubuf
    float* scrf = (float*)Ubuf;
    float4* scr4 = (float4*)Ubuf;                     // [jh][i][k4] f4 = 64 KB (fits 66.5 KB)
    {
        int k4 = tid & 63, jh = tid >> 6;
        #pragma unroll
        for (int i = 0; i < 4; ++i) scr4[(((jh << 2) + i) << 6) + k4] = acc[i];
        if ((tid & 31) == 0) {
            #pragma unroll
            for (int i = 0; i < 4; ++i) sefp[((tid >> 5) << 2) + i] = sefacc[i];
        }
    }
    __syncthreads();
    {
        int k = tid & 255, i = tid >> 8;
        float s = 0.f;
        #pragma unroll
        for (int jh = 0; jh < 16; ++jh) s += scrf[(jh << 10) + (i << 8) + k];
        t_lds[(i << 8) + k] = s;
    }
    if (tid < 4) {
        float ss = 0.f;
        #pragma unroll
        for (int jl = 0; jl < 32; ++jl) ss += sefp[(jl << 2) + tid];
        sef_lds[tid] = ss;
    }
    __syncthreads();
}

// ---------------------------------------------------------------------------
__global__ __launch_bounds__(1024) void k_route(const float* __restrict__ U,
                                                const float* __restrict__ W,
                                                const float* __restrict__ t0p,
                                                float* __restrict__ out) {
    __shared__ __align__(16) float4 Ubuf[2 * TJ * RSTR];   // 66,560 B (+ scrB alias)
    __shared__ float bmat[4 * 1024];                       // 16 KB
    __shared__ __align__(16) float w_lds[4 * 256];
    __shared__ __align__(16) float e_lds[TJ * 4];
    __shared__ __align__(16) float t_lds[4 * 256];
    __shared__ float t0_lds[256];
    __shared__ float spart[16 * 64];
    __shared__ float sefp[TJ * 4];
    __shared__ float sef_lds[4];
    __shared__ __align__(16) float v_lds[4 * 64];

    const int tid = threadIdx.x;
    const int b = blockIdx.x & 31, ig = blockIdx.x >> 5;   // same-b blocks -> same XCD
    const float4* U4b = ((const float4*)U) + ((long)b << 16);

    // iteration-0 t (column mean, shared by all i): sum 16 partials
    if (tid < 256) {
        float a = 0.f;
        const float* tp0 = t0p + (b << 12) + tid;
        #pragma unroll
        for (int q = 0; q < 16; ++q) a += tp0[q << 8];
        t0_lds[tid] = a;
    }
    __syncthreads();

    sv_block(W, t0_lds, 0, sef_lds, 0, spart, v_lds, w_lds, out, 0, b, ig, tid);
    routing_pass(U4b, Ubuf, bmat, e_lds, sefp, sef_lds, t_lds, w_lds, 0, tid);
    sv_block(W, t_lds, 256, sef_lds, 1, spart, v_lds, w_lds, out, 0, b, ig, tid);
    routing_pass(U4b, Ubuf, bmat, e_lds, sefp, sef_lds, t_lds, w_lds, 1, tid);
    sv_block(W, t_lds, 256, sef_lds, 1, spart, v_lds, w_lds, out, 1, b, ig, tid);
}

// ---------------------------------------------------------------------------
extern "C" void kernel_launch(void* const* d_in, const int* in_sizes, int n_in,
                              void* d_out, int out_size, void* d_ws, size_t ws_size,
                              hipStream_t stream) {
    const float* U = (const float*)d_in[0];   // [32,1024,256]
    const float* W = (const float*)d_in[1];   // [256,2048]
    float* out = (float*)d_out;               // [32,32,64]
    float* t0p = (float*)d_ws;                // [32][16][256] = 131,072 floats

    k_colsum<<<dim3(32, 16), 256, 0, stream>>>(U, t0p);
    k_route<<<256, 1024, 0, stream>>>(U, W, t0p, out);
}

// Round 6
// 173.804 us; speedup vs baseline: 1.3790x; 1.2669x over previous
//
#include <hip/hip_runtime.h>
#include <math.h>

// Capsule routing B=32, N=1024(j), D=256(k), NC=32(i), DC=64(d). Factored
// algebra (no u_hat), MFMA-based:
//   delta[j,i] = U[b,j,:].w[:,i]            (k_pass, mfma 16x16x32 bf16 hi/lo)
//   e = exp(bmat), sef = sum_j e            (k_pass, fp32 VALU)
//   t^T[k,i]  += Ut[k,j].e^T[j,i]           (k_pass, mfma, split e/U hi+lo)
//   s = tW ; v = s*rsqrt(||s||^2+eps*sef^2); w = W_i v (hi/lo bf16)  (k_sv)
// Parallelism: block = (b, 16-capsule group g2, 256-j slice p) -> grid 256,
// full 16-wide MFMA tiles. Cross-block j-reduction via tpart/sefpart in ws.
// 6 plain launches, no atomics, no cooperative sync.

typedef short v8s __attribute__((ext_vector_type(8)));
typedef short v4s __attribute__((ext_vector_type(4)));
typedef short v2s __attribute__((ext_vector_type(2)));
typedef float v4f __attribute__((ext_vector_type(4)));

__device__ __forceinline__ unsigned short f2bf(float x) {
    unsigned u = __float_as_uint(x);
    u = u + 0x7fffu + ((u >> 16) & 1u);
    return (unsigned short)(u >> 16);
}
__device__ __forceinline__ float bf2f(unsigned short h) {
    return __uint_as_float(((unsigned)h) << 16);
}

// ---------------------------------------------------------------------------
// colsum partials, iteration-0 uniform c: t0p[b][q][k] = mean over 64 j rows
__global__ __launch_bounds__(256) void k_colsum(const float* __restrict__ U,
                                                float* __restrict__ t0p) {
    int b = blockIdx.x, q = blockIdx.y, k = threadIdx.x;
    const float* Up = U + (((b << 10) + (q << 6)) << 8) + k;
    float acc = 0.f;
    #pragma unroll 16
    for (int jl = 0; jl < 64; ++jl) acc += Up[jl << 8];
    t0p[(b << 12) + (q << 8) + k] = acc * (1.0f / 1024.0f);
}

// ---------------------------------------------------------------------------
// sv: per (b,iG): t[k] (sum of partials), s = tW_i, v = squash, w = W_i v.
// Writes w as bf16 hi/lo for the next pass. grid 1024, block 256.
__global__ __launch_bounds__(256) void k_sv(const float* __restrict__ t0p,
                                            const float* __restrict__ tpart,
                                            const float* __restrict__ sefpart,
                                            const float* __restrict__ W,
                                            short* __restrict__ wbt_h,
                                            short* __restrict__ wbt_l,
                                            float* __restrict__ out,
                                            int mode, int writeOut) {
    __shared__ float t_lds[256];
    __shared__ float spart[256];
    __shared__ __align__(16) float v_lds[64];
    __shared__ float sefv;
    int bid = blockIdx.x, tid = threadIdx.x;
    int b = bid >> 5, iG = bid & 31, g2 = iG >> 4, il = iG & 15;
    int bg = (b << 1) | g2;

    float acc = 0.f;
    if (mode == 0) {
        const float* tb = t0p + (b << 12) + tid;
        #pragma unroll
        for (int q = 0; q < 16; ++q) acc += tb[q << 8];
        if (tid == 0) sefv = 1.0f;
    } else {
        const float* tb = tpart + (((bg << 4) + il) << 8) + tid;
        #pragma unroll
        for (int p = 0; p < 4; ++p) acc += tb[p * 262144];
        if (tid == 0) {
            float s = 0.f;
            #pragma unroll
            for (int q = 0; q < 8; ++q) s += sefpart[(((q << 6) + bg) << 4) + il];
            sefv = s;
        }
    }
    t_lds[tid] = acc;
    __syncthreads();

    // s phase: thread = (d = tid&63, kq = tid>>6)
    int d = tid & 63, kq = tid >> 6;
    const float* Wc = W + ((kq << 6) * 2048) + (iG << 6) + d;
    float s = 0.f;
    #pragma unroll 4
    for (int kk = 0; kk < 64; ++kk)
        s += t_lds[(kq << 6) + kk] * Wc[kk * 2048];
    spart[tid] = s;
    __syncthreads();

    if (tid < 64) {
        float sv = spart[tid] + spart[tid + 64] + spart[tid + 128] + spart[tid + 192];
        float n2 = sv * sv;
        #pragma unroll
        for (int m = 1; m < 64; m <<= 1) n2 += __shfl_xor(n2, m, 64);
        float sf = sefv;
        float v = sv * rsqrtf(n2 + 1e-7f * sf * sf);
        v_lds[tid] = v;
        if (writeOut) out[((bid) << 6) + tid] = v;
    }
    __syncthreads();

    // w phase: thread = k
    int k = tid;
    const float4* Wr = (const float4*)(W + k * 2048 + (iG << 6));
    const float4* v4 = (const float4*)v_lds;
    float w = 0.f;
    #pragma unroll
    for (int q = 0; q < 16; ++q) {
        float4 a = Wr[q], vv = v4[q];
        w += a.x * vv.x + a.y * vv.y + a.z * vv.z + a.w * vv.w;
    }
    unsigned short wh = f2bf(w);
    unsigned short wl = f2bf(w - bf2f(wh));
    int widx = (((bg << 4) + il) << 8) + k;
    wbt_h[widx] = (short)wh;
    wbt_l[widx] = (short)wl;
}

// ---------------------------------------------------------------------------
// stage one (j-pair, 4k) group into the three LDS layouts (hi row-major,
// hi/lo transposed). k0 = lane*4, rows j0, j0+1 (j within 32-j tile).
__device__ __forceinline__ void stage_write(short* Uh, short* Th, short* Tl,
                                            int j0, int k0,
                                            const float4& g0, const float4& g1) {
    float a0[4] = {g0.x, g0.y, g0.z, g0.w};
    float a1[4] = {g1.x, g1.y, g1.z, g1.w};
    unsigned short h0[4], l0[4], h1[4], l1[4];
    #pragma unroll
    for (int e = 0; e < 4; ++e) {
        h0[e] = f2bf(a0[e]); l0[e] = f2bf(a0[e] - bf2f(h0[e]));
        h1[e] = f2bf(a1[e]); l1[e] = f2bf(a1[e] - bf2f(h1[e]));
    }
    *(v4s*)&Uh[j0 * 264 + k0] =
        (v4s){(short)h0[0], (short)h0[1], (short)h0[2], (short)h0[3]};
    *(v4s*)&Uh[(j0 + 1) * 264 + k0] =
        (v4s){(short)h1[0], (short)h1[1], (short)h1[2], (short)h1[3]};
    #pragma unroll
    for (int e = 0; e < 4; ++e) {
        *(v2s*)&Th[(k0 + e) * 40 + j0] = (v2s){(short)h0[e], (short)h1[e]};
        *(v2s*)&Tl[(k0 + e) * 40 + j0] = (v2s){(short)l0[e], (short)l1[e]};
    }
}

// ---------------------------------------------------------------------------
// pass: per block (b, p=256-j slice, g2=16-capsule group):
//   per 32-j tile: delta-MFMA (waves 0-1) -> exp -> e hi/lo; t-MFMA (16 waves,
//   one 16-k M-tile each) accumulating in AGPRs across the 8 tiles.
// Outputs: bmatg logits (pass 1), tpart[p], sefpart[p*2+wv].
__global__ __launch_bounds__(1024) void k_pass(const float* __restrict__ U,
                                               const short* __restrict__ wbt_h,
                                               const short* __restrict__ wbt_l,
                                               float* __restrict__ bmatg,
                                               float* __restrict__ tpart,
                                               float* __restrict__ sefpart,
                                               int addold) {
    __shared__ short s_Uh[2][32 * 264];    // U hi, [j][k] k-contig (delta A)
    __shared__ short s_Th[2][256 * 40];    // U hi, [k][j] j-contig (t A)
    __shared__ short s_Tl[2][256 * 40];    // U lo, [k][j]
    __shared__ short s_wh[16 * 264];       // w hi, [i][k]  (delta B)
    __shared__ short s_wl[16 * 264];       // w lo, [i][k]
    __shared__ short s_eh[16 * 40];        // e hi, [i][j]  (t B)
    __shared__ short s_el[16 * 40];        // e lo, [i][j]

    const int tid = threadIdx.x;
    const int wv = tid >> 6, lane = tid & 63;
    const int quad = lane >> 4, nn = lane & 15;
    const int blk = blockIdx.x;
    const int b = blk >> 3, p = (blk >> 1) & 3, g2 = blk & 1;
    const int bg = (b << 1) | g2;
    const int rowbase = (b << 10) + (p << 8);
    const float4* U4 = (const float4*)U;

    // stage w hi/lo -> LDS
    if (tid < 512) {
        int row = tid >> 5, seg = tid & 31;
        int gidx = (((bg << 4) + row) << 8) + (seg << 3);
        *(v8s*)&s_wh[row * 264 + (seg << 3)] = *(const v8s*)(wbt_h + gidx);
        *(v8s*)&s_wl[row * 264 + (seg << 3)] = *(const v8s*)(wbt_l + gidx);
    }
    // prologue: stage tile 0 into buffer 0
    {
        int j0 = wv << 1;
        float4 g0 = U4[(rowbase + j0) * 64 + lane];
        float4 g1 = U4[(rowbase + j0 + 1) * 64 + lane];
        stage_write(s_Uh[0], s_Th[0], s_Tl[0], j0, lane << 2, g0, g1);
    }
    __syncthreads();

    v4f acc = {0.f, 0.f, 0.f, 0.f};
    float sefacc = 0.f;
    const int jg0 = p << 8;

    for (int t = 0; t < 8; ++t) {
        const int cur = t & 1;
        float4 g0, g1;
        if (t < 7) {
            int j0 = wv << 1;
            int r = (rowbase + ((t + 1) << 5) + j0) * 64 + lane;
            g0 = U4[r];
            g1 = U4[r + 64];
        }
        if (wv < 2) {
            // delta: D[j,i], M-tile = j 16wv..16wv+15, K=256, hi/lo-w splits
            float bold[4];
            if (addold) {
                #pragma unroll
                for (int r = 0; r < 4; ++r) {
                    int j_loc = (wv << 4) + (quad << 2) + r;
                    bold[r] = bmatg[(((b << 5) + (g2 << 4) + nn) << 10) +
                                    jg0 + (t << 5) + j_loc];
                }
            }
            const short* uhb = &s_Uh[cur][((wv << 4) + nn) * 264 + (quad << 3)];
            const short* whb = &s_wh[nn * 264 + (quad << 3)];
            const short* wlb = &s_wl[nn * 264 + (quad << 3)];
            v4f d1 = {0.f, 0.f, 0.f, 0.f}, d2 = {0.f, 0.f, 0.f, 0.f};
            #pragma unroll
            for (int ks = 0; ks < 8; ++ks) {
                v8s a  = *(const v8s*)(uhb + (ks << 5));
                v8s bh = *(const v8s*)(whb + (ks << 5));
                v8s bl = *(const v8s*)(wlb + (ks << 5));
                d1 = __builtin_amdgcn_mfma_f32_16x16x32_bf16(a, bh, d1, 0, 0, 0);
                d2 = __builtin_amdgcn_mfma_f32_16x16x32_bf16(a, bl, d2, 0, 0, 0);
            }
            #pragma unroll
            for (int r = 0; r < 4; ++r) {
                int j_loc = (wv << 4) + (quad << 2) + r;
                float logit = d1[r] + d2[r];
                int gaddr = (((b << 5) + (g2 << 4) + nn) << 10) + jg0 + (t << 5) + j_loc;
                if (addold) logit += bold[r];
                else bmatg[gaddr] = logit;
                float e = __expf(logit);
                sefacc += e;
                unsigned short ehv = f2bf(e);
                s_eh[nn * 40 + j_loc] = (short)ehv;
                s_el[nn * 40 + j_loc] = (short)f2bf(e - bf2f(ehv));
            }
        }
        if (t < 7) {
            int j0 = wv << 1;
            stage_write(s_Uh[cur ^ 1], s_Th[cur ^ 1], s_Tl[cur ^ 1],
                        j0, lane << 2, g0, g1);
        }
        __syncthreads();   // e(t) + stage(t+1) visible
        // t-MFMA: wave's M-tile = k rows 16wv..16wv+15, K = 32 j (one mfma)
        {
            v8s ah  = *(const v8s*)&s_Th[cur][((wv << 4) + nn) * 40 + (quad << 3)];
            v8s al  = *(const v8s*)&s_Tl[cur][((wv << 4) + nn) * 40 + (quad << 3)];
            v8s beh = *(const v8s*)&s_eh[nn * 40 + (quad << 3)];
            v8s bel = *(const v8s*)&s_el[nn * 40 + (quad << 3)];
            acc = __builtin_amdgcn_mfma_f32_16x16x32_bf16(ah, beh, acc, 0, 0, 0);
            acc = __builtin_amdgcn_mfma_f32_16x16x32_bf16(al, beh, acc, 0, 0, 0);
            acc = __builtin_amdgcn_mfma_f32_16x16x32_bf16(ah, bel, acc, 0, 0, 0);
        }
        __syncthreads();   // buf[cur] reads done before next overwrite
    }

    // write t partials: D row = k-local = quad*4+reg, col = i = nn
    #pragma unroll
    for (int r = 0; r < 4; ++r) {
        int k = (wv << 4) + (quad << 2) + r;
        tpart[((((p << 6) + bg) << 4) + nn) * 256 + k] = acc[r];
    }
    // sef partials (delta waves only): reduce over quads
    if (wv < 2) {
        float se = sefacc;
        se += __shfl_xor(se, 16, 64);
        se += __shfl_xor(se, 32, 64);
        if (lane < 16)
            sefpart[(((((p << 1) + wv) << 6) + bg) << 4) + lane] = se;
    }
}

// ---------------------------------------------------------------------------
extern "C" void kernel_launch(void* const* d_in, const int* in_sizes, int n_in,
                              void* d_out, int out_size, void* d_ws, size_t ws_size,
                              hipStream_t stream) {
    const float* U = (const float*)d_in[0];   // [32,1024,256]
    const float* W = (const float*)d_in[1];   // [256,2048]
    float* out = (float*)d_out;               // [32,32,64]
    float* ws = (float*)d_ws;

    // ws layout (float slots), total ~2.50M floats = 10 MB
    float* t0p     = ws;                    // [32][16][256]   = 131,072
    float* bmatg   = t0p + 131072;          // [32][32][1024]  = 1,048,576
    float* tpart   = bmatg + 1048576;       // [4][64][16][256]= 1,048,576
    float* sefpart = tpart + 1048576;       // [8][64][16]     = 8,192
    short* wbt_h   = (short*)(sefpart + 8192);      // [64][16][256] shorts
    short* wbt_l   = wbt_h + 262144;

    k_colsum<<<dim3(32, 16), 256, 0, stream>>>(U, t0p);
    k_sv<<<1024, 256, 0, stream>>>(t0p, tpart, sefpart, W, wbt_h, wbt_l, out, 0, 0);
    k_pass<<<256, 1024, 0, stream>>>(U, wbt_h, wbt_l, bmatg, tpart, sefpart, 0);
    k_sv<<<1024, 256, 0, stream>>>(t0p, tpart, sefpart, W, wbt_h, wbt_l, out, 1, 0);
    k_pass<<<256, 1024, 0, stream>>>(U, wbt_h, wbt_l, bmatg, tpart, sefpart, 1);
    k_sv<<<1024, 256, 0, stream>>>(t0p, tpart, sefpart, W, wbt_h, wbt_l, out, 1, 1);
}